// Round 1
// baseline (741.064 us; speedup 1.0000x reference)
//
#include <hip/hip_runtime.h>

// Slater-determinant ordered sampler, D=512 sites, N=128 particles.
//
// Reformulated from the reference's D x D bordered-inverse scan to an
// N x N inverse-block recursion (det(I-UU^T) = det(I-U^T U) identity):
//   A_0 = I_N;  per site i with p = P[i,:]:
//     w = A p;  s = 1 - p.w   (== reference Schur pivot s_i)
//     <identical decision logic>
//     A += w w^T / pivot,  pivot = s - occupy   (unified update; verified
//     algebraically: occupy case = -qq^T update followed by bordering)
// State A (128x128 fp32) lives in registers of one 512-thread workgroup:
//   wave v (of 8) owns cols [16v, 16v+16); lane l owns rows {l, l+64}.
// One __syncthreads per step (double-buffered LDS partials + p-row).

#define DD 512
#define NN 128
#define NTHREADS 512

__global__ __launch_bounds__(NTHREADS) void slater_scan_kernel(
    const float* __restrict__ P, const float* __restrict__ u,
    float* __restrict__ out) {
  const int tid  = threadIdx.x;
  const int wave = tid >> 6;
  const int lane = tid & 63;
  const int c0   = wave << 4;  // first column owned by this wave

  __shared__ __align__(16) float pbuf[2][NN];  // staged P rows (double buf)
  __shared__ float2 part[2][8][64];            // per-wave matvec partials
  __shared__ float ush[NN];                    // u preloaded

  // Zero cond_probs region (harness poisons d_out with 0xAA).
  for (int j = tid; j < NN * DD; j += NTHREADS) out[j] = 0.0f;
  if (tid < NN) {
    ush[tid]     = u[tid];
    pbuf[0][tid] = P[tid];  // row 0
  }

  // A = I_N distributed into registers.
  float A0[16], A1[16];
#pragma unroll
  for (int j = 0; j < 16; ++j) {
    A0[j] = (lane == c0 + j) ? 1.0f : 0.0f;
    A1[j] = (lane + 64 == c0 + j) ? 1.0f : 0.0f;
  }

  // Decision state, replicated bit-identically in every thread.
  float ratio = 1.0f, cumul = 0.0f;
  int k = 0;

  __syncthreads();

  for (int i = 0; i < DD; ++i) {
    const int buf = i & 1;

    // Early-issue next P row load (consumed just before the barrier).
    float pnext = 0.0f;
    const bool stager = (tid < NN) && (i + 1 < DD);
    if (stager) pnext = P[(i + 1) * NN + tid];

    // This wave's 16 p values (uniform-address LDS reads -> broadcast).
    const float4* pb4 = (const float4*)(&pbuf[buf][0]);
    const float4 q0 = pb4[(wave << 2) + 0];
    const float4 q1 = pb4[(wave << 2) + 1];
    const float4 q2 = pb4[(wave << 2) + 2];
    const float4 q3 = pb4[(wave << 2) + 3];
    const float pc[16] = {q0.x, q0.y, q0.z, q0.w, q1.x, q1.y, q1.z, q1.w,
                          q2.x, q2.y, q2.z, q2.w, q3.x, q3.y, q3.z, q3.w};

    // p values for the s-dot (rows owned by this lane).
    const float p_r0 = pbuf[buf][lane];
    const float p_r1 = pbuf[buf][lane + 64];

    // Partial matvec over this wave's 16 columns.
    float pa0 = 0.0f, pa1 = 0.0f;
#pragma unroll
    for (int j = 0; j < 16; ++j) {
      pa0 = fmaf(A0[j], pc[j], pa0);
      pa1 = fmaf(A1[j], pc[j], pa1);
    }
    part[buf][wave][lane] = make_float2(pa0, pa1);
    if (stager) pbuf[buf ^ 1][tid] = pnext;
    __syncthreads();  // the only barrier per step

    // w for this lane's two rows (sum of 8 wave partials; identical order
    // in every wave -> bit-identical).
    float wl = 0.0f, wh = 0.0f;
#pragma unroll
    for (int v = 0; v < 8; ++v) {
      const float2 t = part[buf][v][lane];
      wl += t.x;
      wh += t.y;
    }

    // s = 1 - p.w, reduced redundantly per wave (butterfly, 64 lanes).
    float sd = fmaf(p_r0, wl, p_r1 * wh);
#pragma unroll
    for (int off = 32; off; off >>= 1) sd += __shfl_xor(sd, off, 64);
    const float s = 1.0f - sd;

    // Decision logic — mirrors the reference exactly.
    const int last_allowed = DD - NN + k;
    const bool active = (k < NN) && (i <= last_allowed);
    const float pr = active ? (-(s - 1.0f) * ratio) : 0.0f;
    const float uk = ush[(k < NN) ? k : (NN - 1)];
    const bool occupy = active && ((cumul + pr >= uk) || (i == last_allowed));
    float pivot = occupy ? (s - 1.0f) : s;
    pivot = (fabsf(pivot) < 1e-30f) ? 1e-30f : pivot;
    const float invp = 1.0f / pivot;

    if (tid == 0) {
      if (k < NN) out[k * DD + i] = pr;           // cond_probs[k, i]
      if (occupy) out[NN * DD + k] = (float)i;    // positions[k]
    }

    ratio = occupy ? 1.0f : (active ? ratio * s : ratio);
    cumul = occupy ? 0.0f : (cumul + pr);
    k += occupy ? 1 : 0;

    if (k == NN) break;  // uniform across all threads; outputs complete

    // Rank-1 update: A[r,c] += w[r] * w[c] / pivot.
#pragma unroll
    for (int j = 0; j < 16; ++j) {
      const int c = c0 + j;
      const float wc = (c < 64) ? __shfl(wl, c, 64) : __shfl(wh, c - 64, 64);
      const float t = wc * invp;
      A0[j] = fmaf(wl, t, A0[j]);
      A1[j] = fmaf(wh, t, A1[j]);
    }
  }
}

extern "C" void kernel_launch(void* const* d_in, const int* in_sizes, int n_in,
                              void* d_out, int out_size, void* d_ws,
                              size_t ws_size, hipStream_t stream) {
  const float* P = (const float*)d_in[0];  // (512, 128) row-major fp32
  const float* u = (const float*)d_in[1];  // (128,) fp32
  float* out = (float*)d_out;              // 65536 cond_probs + 128 positions
  hipLaunchKernelGGL(slater_scan_kernel, dim3(1), dim3(NTHREADS), 0, stream,
                     P, u, out);
}